// Round 1
// baseline (1601.530 us; speedup 1.0000x reference)
//
#include <hip/hip_runtime.h>
#include <math.h>

typedef float f4 __attribute__((ext_vector_type(4)));

#define S_ 2048
#define B_ 4
#define D_ 1024

constexpr int BM = 128, BN = 128, BK = 8;

// C[m][n] = alpha * sum_k A[m][k]*B[n][k] (+ bias[n])
// XMAP: A rows are gathered from x laid out (S,B,D): row m=(b*S+s) -> x[(s*B+b)*D + k]
template<bool XMAP, bool BIAS>
__global__ __launch_bounds__(256)
void gemm_nt(const float* __restrict__ A, const float* __restrict__ Bmat,
             const float* __restrict__ bias, float* __restrict__ C,
             int M, int N, int K, float alpha,
             size_t sA, size_t sB, size_t sC)
{
    A    += blockIdx.z * sA;
    Bmat += blockIdx.z * sB;
    C    += blockIdx.z * sC;

    __shared__ float As[BK][BM];
    __shared__ float Bs[BK][BN];

    const int t  = threadIdx.x;
    const int tx = t & 15, ty = t >> 4;
    const int m0 = blockIdx.x * BM, n0 = blockIdx.y * BN;

    // staging indices: thread t loads float4 of row (t>>1), k-offset (t&1)*4
    const int ar = t >> 1;
    const int ak = (t & 1) * 4;
    const float* aptr;
    {
        int am = m0 + ar;
        if (XMAP) {
            int b = am >> 11;          // S_=2048
            int s = am & (S_ - 1);
            aptr = A + (size_t)(s * B_ + b) * D_ + ak;
        } else {
            aptr = A + (size_t)am * K + ak;
        }
    }
    const float* bptr = Bmat + (size_t)(n0 + ar) * K + ak;

    float acc[8][8];
#pragma unroll
    for (int i = 0; i < 8; i++)
#pragma unroll
        for (int j = 0; j < 8; j++) acc[i][j] = 0.f;

    for (int k0 = 0; k0 < K; k0 += BK) {
        f4 av = *(const f4*)(aptr + k0);
        f4 bv = *(const f4*)(bptr + k0);
        __syncthreads();
#pragma unroll
        for (int j = 0; j < 4; j++) As[ak + j][ar] = av[j];
#pragma unroll
        for (int j = 0; j < 4; j++) Bs[ak + j][ar] = bv[j];
        __syncthreads();
#pragma unroll
        for (int kk = 0; kk < BK; kk++) {
            const f4 a0 = *(const f4*)&As[kk][ty * 8];
            const f4 a1 = *(const f4*)&As[kk][ty * 8 + 4];
            const f4 b0 = *(const f4*)&Bs[kk][tx * 8];
            const f4 b1 = *(const f4*)&Bs[kk][tx * 8 + 4];
            float a_[8] = {a0[0], a0[1], a0[2], a0[3], a1[0], a1[1], a1[2], a1[3]};
            float b_[8] = {b0[0], b0[1], b0[2], b0[3], b1[0], b1[1], b1[2], b1[3]};
#pragma unroll
            for (int i = 0; i < 8; i++)
#pragma unroll
                for (int j = 0; j < 8; j++)
                    acc[i][j] = fmaf(a_[i], b_[j], acc[i][j]);
        }
    }

    f4 bb0 = (f4)0.f, bb1 = (f4)0.f;
    if (BIAS) {
        bb0 = *(const f4*)&bias[n0 + tx * 8];
        bb1 = *(const f4*)&bias[n0 + tx * 8 + 4];
    }
#pragma unroll
    for (int i = 0; i < 8; i++) {
        size_t m = (size_t)(m0 + ty * 8 + i);
        float* crow = C + m * N + n0 + tx * 8;
        f4 c0, c1;
#pragma unroll
        for (int j = 0; j < 4; j++) {
            c0[j] = acc[i][j] * alpha;
            c1[j] = acc[i][4 + j] * alpha;
        }
        if (BIAS) { c0 += bb0; c1 += bb1; }
        *(f4*)crow = c0;
        *(f4*)(crow + 4) = c1;
    }
}

// C[m][n] = sum_k A[m][k]*B[k][n]   (A row-major MxK, B row-major KxN)
__global__ __launch_bounds__(256)
void gemm_nn(const float* __restrict__ A, const float* __restrict__ Bmat,
             float* __restrict__ C, int M, int N, int K,
             size_t sA, size_t sB, size_t sC)
{
    A    += blockIdx.z * sA;
    Bmat += blockIdx.z * sB;
    C    += blockIdx.z * sC;

    __shared__ float As[BK][BM];
    __shared__ float Bs[BK][BN];

    const int t  = threadIdx.x;
    const int tx = t & 15, ty = t >> 4;
    const int m0 = blockIdx.x * BM, n0 = blockIdx.y * BN;

    const int ar = t >> 1;
    const int ak = (t & 1) * 4;
    const float* aptr = A + (size_t)(m0 + ar) * K + ak;

    const int bkr = t >> 5;         // 0..7
    const int bnc = (t & 31) * 4;   // 0..124
    const float* bptr = Bmat + (size_t)bkr * N + n0 + bnc;

    float acc[8][8];
#pragma unroll
    for (int i = 0; i < 8; i++)
#pragma unroll
        for (int j = 0; j < 8; j++) acc[i][j] = 0.f;

    for (int k0 = 0; k0 < K; k0 += BK) {
        f4 av = *(const f4*)(aptr + k0);
        f4 bv = *(const f4*)(bptr + (size_t)k0 * N);
        __syncthreads();
#pragma unroll
        for (int j = 0; j < 4; j++) As[ak + j][ar] = av[j];
        *(f4*)&Bs[bkr][bnc] = bv;
        __syncthreads();
#pragma unroll
        for (int kk = 0; kk < BK; kk++) {
            const f4 a0 = *(const f4*)&As[kk][ty * 8];
            const f4 a1 = *(const f4*)&As[kk][ty * 8 + 4];
            const f4 b0 = *(const f4*)&Bs[kk][tx * 8];
            const f4 b1 = *(const f4*)&Bs[kk][tx * 8 + 4];
            float a_[8] = {a0[0], a0[1], a0[2], a0[3], a1[0], a1[1], a1[2], a1[3]};
            float b_[8] = {b0[0], b0[1], b0[2], b0[3], b1[0], b1[1], b1[2], b1[3]};
#pragma unroll
            for (int i = 0; i < 8; i++)
#pragma unroll
                for (int j = 0; j < 8; j++)
                    acc[i][j] = fmaf(a_[i], b_[j], acc[i][j]);
        }
    }

#pragma unroll
    for (int i = 0; i < 8; i++) {
        size_t m = (size_t)(m0 + ty * 8 + i);
        float* crow = C + m * N + n0 + tx * 8;
        f4 c0, c1;
#pragma unroll
        for (int j = 0; j < 4; j++) {
            c0[j] = acc[i][j];
            c1[j] = acc[i][4 + j];
        }
        *(f4*)crow = c0;
        *(f4*)(crow + 4) = c1;
    }
}

// in-place row softmax over rows of length S_
__global__ __launch_bounds__(256)
void softmax_rows(float* __restrict__ P)
{
    float* p = P + (size_t)blockIdx.x * S_;
    const int t = threadIdx.x;

    f4 v0 = *(f4*)&p[t * 8];
    f4 v1 = *(f4*)&p[t * 8 + 4];

    float mx = v0[0];
#pragma unroll
    for (int j = 0; j < 4; j++) { mx = fmaxf(mx, v0[j]); mx = fmaxf(mx, v1[j]); }
#pragma unroll
    for (int off = 32; off > 0; off >>= 1) mx = fmaxf(mx, __shfl_xor(mx, off));

    __shared__ float rmax[4], rsum[4];
    if ((t & 63) == 0) rmax[t >> 6] = mx;
    __syncthreads();
    mx = fmaxf(fmaxf(rmax[0], rmax[1]), fmaxf(rmax[2], rmax[3]));

    float sum = 0.f;
#pragma unroll
    for (int j = 0; j < 4; j++) {
        v0[j] = expf(v0[j] - mx); sum += v0[j];
        v1[j] = expf(v1[j] - mx); sum += v1[j];
    }
#pragma unroll
    for (int off = 32; off > 0; off >>= 1) sum += __shfl_xor(sum, off);
    if ((t & 63) == 0) rsum[t >> 6] = sum;
    __syncthreads();
    sum = rsum[0] + rsum[1] + rsum[2] + rsum[3];

    float inv = 1.f / sum;
    v0 *= inv; v1 *= inv;
    *(f4*)&p[t * 8] = v0;
    *(f4*)&p[t * 8 + 4] = v1;
}

extern "C" void kernel_launch(void* const* d_in, const int* in_sizes, int n_in,
                              void* d_out, int out_size, void* d_ws, size_t ws_size,
                              hipStream_t stream)
{
    const float* x  = (const float*)d_in[0];
    const float* Wq = (const float*)d_in[1];
    const float* bq = (const float*)d_in[2];
    const float* Wk = (const float*)d_in[3];
    const float* bk = (const float*)d_in[4];
    const float* Wv = (const float*)d_in[5];
    const float* bv = (const float*)d_in[6];
    float* out = (float*)d_out;

    const size_t nQKV = (size_t)B_ * S_ * D_;   // 8388608 elems = 32 MB
    const size_t nSC  = (size_t)B_ * S_ * S_;   // 16777216 elems = 64 MB
    if (ws_size < (3 * nQKV + nSC) * sizeof(float)) return;  // need 160 MB

    float* q  = (float*)d_ws;
    float* k  = q + nQKV;
    float* v  = k + nQKV;
    float* sc = v + nQKV;

    dim3 blk(256, 1, 1);

    // Phase 1: QKV projections. M = B*S = 8192, N = K = D.
    dim3 g1(8192 / BM, D_ / BN, 1);
    gemm_nt<true, true><<<g1, blk, 0, stream>>>(x, Wq, bq, q, 8192, D_, D_, 1.f, 0, 0, 0);
    gemm_nt<true, true><<<g1, blk, 0, stream>>>(x, Wk, bk, k, 8192, D_, D_, 1.f, 0, 0, 0);
    gemm_nt<true, true><<<g1, blk, 0, stream>>>(x, Wv, bv, v, 8192, D_, D_, 1.f, 0, 0, 0);

    // Phase 2: scores = scale * q @ k^T, per batch (z).
    dim3 g2(S_ / BM, S_ / BN, B_);
    const float scale = 0.03125f;  // 1/sqrt(1024)
    gemm_nt<false, false><<<g2, blk, 0, stream>>>(q, k, nullptr, sc, S_, S_, D_, scale,
                                                  (size_t)S_ * D_, (size_t)S_ * D_, (size_t)S_ * S_);

    // Phase 3: row softmax in place.
    softmax_rows<<<dim3(B_ * S_, 1, 1), blk, 0, stream>>>(sc);

    // Phase 4: out = attn @ v, per batch; writes d_out directly
    // (reference reshape (B,S,D)->(S,B,D) is a flat reinterpret).
    dim3 g4(S_ / BM, D_ / BN, B_);
    gemm_nn<<<g4, blk, 0, stream>>>(sc, v, out, S_, D_, S_,
                                    (size_t)S_ * S_, (size_t)S_ * D_, (size_t)S_ * D_);
}

// Round 2
// 324.555 us; speedup vs baseline: 4.9345x; 4.9345x over previous
//
#include <hip/hip_runtime.h>
#include <math.h>

typedef float  f4   __attribute__((ext_vector_type(4)));
typedef float  f32x4 __attribute__((ext_vector_type(4)));
typedef short  bf16x8 __attribute__((ext_vector_type(8)));
typedef unsigned short u16x8 __attribute__((ext_vector_type(8)));

#define S_ 2048
#define B_ 4
#define D_ 1024

__device__ __forceinline__ unsigned short f2bf(float f) {
    unsigned u = __builtin_bit_cast(unsigned, f);
    u = (u + 0x7FFFu + ((u >> 16) & 1u)) >> 16;
    return (unsigned short)u;
}

#define GLOAD16(gsrc, ldst) \
    __builtin_amdgcn_global_load_lds((const __attribute__((address_space(1))) void*)(gsrc), \
                                     (__attribute__((address_space(3))) void*)(ldst), 16, 0, 0)

// ---------------------------------------------------------------------------
// Converters
// ---------------------------------------------------------------------------

// x (S,B,D) f32 -> xb (B,S,D) bf16.  blockIdx.x = s*B + b, 128 threads, 8 elem/thread
__global__ __launch_bounds__(128)
void convert_x(const float* __restrict__ x, unsigned short* __restrict__ xb)
{
    const int bid = blockIdx.x;
    const int b = bid & (B_ - 1);
    const int s = bid >> 2;
    const int t = threadIdx.x;
    const float* in = x + (size_t)bid * D_ + t * 8;
    unsigned short* out = xb + ((size_t)b * S_ + s) * D_ + t * 8;
    f4 lo = *(const f4*)in;
    f4 hi = *(const f4*)(in + 4);
    u16x8 o;
#pragma unroll
    for (int j = 0; j < 4; j++) { o[j] = f2bf(lo[j]); o[4 + j] = f2bf(hi[j]); }
    *(u16x8*)out = o;
}

// W (D,D) f32 -> bf16, z selects matrix
__global__ __launch_bounds__(256)
void convert_w(const float* __restrict__ W0, const float* __restrict__ W1,
               const float* __restrict__ W2, unsigned short* __restrict__ dst)
{
    const float* src = (blockIdx.z == 0) ? W0 : (blockIdx.z == 1) ? W1 : W2;
    unsigned short* d = dst + (size_t)blockIdx.z * D_ * D_;
    size_t i = ((size_t)blockIdx.x * 256 + threadIdx.x) * 8;
    f4 lo = *(const f4*)(src + i);
    f4 hi = *(const f4*)(src + i + 4);
    u16x8 o;
#pragma unroll
    for (int j = 0; j < 4; j++) { o[j] = f2bf(lo[j]); o[4 + j] = f2bf(hi[j]); }
    *(u16x8*)(d + i) = o;
}

// vb (B,S,D) bf16 -> vt (B,D,S) bf16, 64x64 tiles
__global__ __launch_bounds__(256)
void transpose_v(const unsigned short* __restrict__ vb, unsigned short* __restrict__ vt)
{
    __shared__ unsigned short tile[64][66];
    const int t = threadIdx.x;
    const int s0 = blockIdx.x * 64, d0 = blockIdx.y * 64, b = blockIdx.z;
    const int rr = t >> 3, c8 = (t & 7) * 8;
#pragma unroll
    for (int p = 0; p < 2; p++) {
        int r = rr + p * 32;
        u16x8 v = *(const u16x8*)(vb + ((size_t)b * S_ + s0 + r) * D_ + d0 + c8);
#pragma unroll
        for (int j = 0; j < 8; j++) tile[r][c8 + j] = v[j];
    }
    __syncthreads();
#pragma unroll
    for (int p = 0; p < 2; p++) {
        int r = rr + p * 32;   // d index within tile
        u16x8 o;
#pragma unroll
        for (int j = 0; j < 8; j++) o[j] = tile[c8 + j][r];
        *(u16x8*)(vt + ((size_t)b * D_ + d0 + r) * S_ + s0 + c8) = o;
    }
}

// ---------------------------------------------------------------------------
// m97-style bf16 NT GEMM: C[m][n] = alpha * sum_k A[m][k]*B[n][k] (+bias[n])
// A: M x K rows (lda), B: N x K rows (ldb), both bf16.  128x128 tile, BK=32.
// OBF16: store bf16, else f32.
// ---------------------------------------------------------------------------
template<bool BIAS, bool OBF16>
__global__ __launch_bounds__(256)
void gemm_bt(const unsigned short* __restrict__ A, const unsigned short* __restrict__ B,
             const float* __restrict__ bias, void* __restrict__ C,
             int lda, int ldb, int ldc, int K, float alpha,
             size_t sA, size_t sB, size_t sC)
{
    __shared__ unsigned short sm[8192];          // As: [0,4096) 128x32, Bs: [4096,8192)

    const unsigned short* Ab = A + blockIdx.z * sA;
    const unsigned short* Bb = B + blockIdx.z * sB;

    const int t   = threadIdx.x;
    const int w   = t >> 6;          // wave 0..3
    const int ln  = t & 63;
    const int m0  = blockIdx.x * 128;
    const int n0  = blockIdx.y * 128;
    const int wm  = (w >> 1) * 64;
    const int wn  = (w & 1) * 64;
    const int c15 = ln & 15;
    const int k16 = ln >> 4;         // 0..3

    // staging sources (bytes), loop-invariant bases
    const char* srcA0 = (const char*)(Ab + (size_t)(m0 + 32 * w +      (ln >> 2)) * lda + (ln & 3) * 8);
    const char* srcA1 = (const char*)(Ab + (size_t)(m0 + 32 * w + 16 + (ln >> 2)) * lda + (ln & 3) * 8);
    const char* srcB0 = (const char*)(Bb + (size_t)(n0 + 32 * w +      (ln >> 2)) * ldb + (ln & 3) * 8);
    const char* srcB1 = (const char*)(Bb + (size_t)(n0 + 32 * w + 16 + (ln >> 2)) * ldb + (ln & 3) * 8);

    unsigned short* ldsA0 = &sm[(2 * w) * 512];
    unsigned short* ldsA1 = &sm[(2 * w + 1) * 512];
    unsigned short* ldsB0 = &sm[4096 + (2 * w) * 512];
    unsigned short* ldsB1 = &sm[4096 + (2 * w + 1) * 512];

    // fragment LDS offsets (ushort idx), loop-invariant
    const int offA = (wm + c15) * 32 + k16 * 8;
    const int offB = 4096 + (wn + c15) * 32 + k16 * 8;

    f32x4 acc[4][4];
#pragma unroll
    for (int i = 0; i < 4; i++)
#pragma unroll
        for (int j = 0; j < 4; j++) acc[i][j] = (f32x4)0.f;

    for (int k0 = 0; k0 < K; k0 += 32) {
        size_t kb = (size_t)k0 * 2;
        GLOAD16(srcA0 + kb, ldsA0);
        GLOAD16(srcA1 + kb, ldsA1);
        GLOAD16(srcB0 + kb, ldsB0);
        GLOAD16(srcB1 + kb, ldsB1);
        __syncthreads();

        bf16x8 af[4], bf[4];
#pragma unroll
        for (int i = 0; i < 4; i++) af[i] = *(const bf16x8*)&sm[offA + i * 512];
#pragma unroll
        for (int j = 0; j < 4; j++) bf[j] = *(const bf16x8*)&sm[offB + j * 512];
#pragma unroll
        for (int i = 0; i < 4; i++)
#pragma unroll
            for (int j = 0; j < 4; j++)
                acc[i][j] = __builtin_amdgcn_mfma_f32_16x16x32_bf16(af[i], bf[j], acc[i][j], 0, 0, 0);
        __syncthreads();
    }

    float bv[4];
#pragma unroll
    for (int j = 0; j < 4; j++)
        bv[j] = BIAS ? bias[n0 + wn + j * 16 + c15] : 0.f;

#pragma unroll
    for (int i = 0; i < 4; i++) {
#pragma unroll
        for (int j = 0; j < 4; j++) {
            int col = n0 + wn + j * 16 + c15;
#pragma unroll
            for (int r = 0; r < 4; r++) {
                int row = m0 + wm + i * 16 + k16 * 4 + r;
                float vv = acc[i][j][r] * alpha + bv[j];
                if (OBF16)
                    ((unsigned short*)C + blockIdx.z * sC)[(size_t)row * ldc + col] = f2bf(vv);
                else
                    ((float*)C + blockIdx.z * sC)[(size_t)row * ldc + col] = vv;
            }
        }
    }
}

// ---------------------------------------------------------------------------
// Row softmax: read f32 row of 2048, write bf16 row IN PLACE (first 4KB of row)
// ---------------------------------------------------------------------------
__global__ __launch_bounds__(256)
void softmax_rows(float* __restrict__ P)
{
    float* p = P + (size_t)blockIdx.x * S_;
    const int t = threadIdx.x;

    f4 v0 = *(f4*)&p[t * 8];
    f4 v1 = *(f4*)&p[t * 8 + 4];

    float mx = v0[0];
#pragma unroll
    for (int j = 0; j < 4; j++) { mx = fmaxf(mx, v0[j]); mx = fmaxf(mx, v1[j]); }
#pragma unroll
    for (int off = 32; off > 0; off >>= 1) mx = fmaxf(mx, __shfl_xor(mx, off));

    __shared__ float rmax[4], rsum[4];
    if ((t & 63) == 0) rmax[t >> 6] = mx;
    __syncthreads();
    mx = fmaxf(fmaxf(rmax[0], rmax[1]), fmaxf(rmax[2], rmax[3]));

    float sum = 0.f;
#pragma unroll
    for (int j = 0; j < 4; j++) {
        v0[j] = __expf(v0[j] - mx); sum += v0[j];
        v1[j] = __expf(v1[j] - mx); sum += v1[j];
    }
#pragma unroll
    for (int off = 32; off > 0; off >>= 1) sum += __shfl_xor(sum, off);
    if ((t & 63) == 0) rsum[t >> 6] = sum;
    __syncthreads();
    sum = rsum[0] + rsum[1] + rsum[2] + rsum[3];

    float inv = 1.f / sum;
    unsigned short* ob = (unsigned short*)p;   // in-place bf16 row, stride 4096 ushorts
    u16x8 o;
#pragma unroll
    for (int j = 0; j < 4; j++) { o[j] = f2bf(v0[j] * inv); o[4 + j] = f2bf(v1[j] * inv); }
    __syncthreads();                            // all reads done before overwrite
    *(u16x8*)&ob[t * 8] = o;
}

// ---------------------------------------------------------------------------

extern "C" void kernel_launch(void* const* d_in, const int* in_sizes, int n_in,
                              void* d_out, int out_size, void* d_ws, size_t ws_size,
                              hipStream_t stream)
{
    const float* x  = (const float*)d_in[0];
    const float* Wq = (const float*)d_in[1];
    const float* bq = (const float*)d_in[2];
    const float* Wk = (const float*)d_in[3];
    const float* bk = (const float*)d_in[4];
    const float* Wv = (const float*)d_in[5];
    const float* bv = (const float*)d_in[6];
    float* out = (float*)d_out;

    const size_t nTok = (size_t)B_ * S_;          // 8192
    const size_t nQKV = nTok * D_;                // 8.39e6
    char* ws = (char*)d_ws;

    unsigned short* xb = (unsigned short*)ws;                     ws += nQKV * 2;       // 16 MB
    unsigned short* wb = (unsigned short*)ws;                     ws += 3 * D_ * D_ * 2; // 6 MB
    unsigned short* qb = (unsigned short*)ws;                     ws += nQKV * 2;       // 16 MB
    unsigned short* kb = (unsigned short*)ws;                     ws += nQKV * 2;       // 16 MB
    unsigned short* vb = (unsigned short*)ws;                     ws += nQKV * 2;       // 16 MB
    unsigned short* vt = (unsigned short*)ws;                     ws += nQKV * 2;       // 16 MB
    float*          sc = (float*)ws;                              ws += (size_t)B_ * S_ * S_ * 4; // 64 MB
    if ((size_t)(ws - (char*)d_ws) > ws_size) return;             // 150 MB total

    dim3 blk(256, 1, 1);

    convert_x<<<dim3(S_ * B_, 1, 1), dim3(128, 1, 1), 0, stream>>>(x, xb);
    convert_w<<<dim3(512, 1, 3), blk, 0, stream>>>(Wq, Wk, Wv, wb);

    // QKV projections: M = 8192, N = K = 1024
    dim3 g1(64, 8, 1);
    gemm_bt<true, true><<<g1, blk, 0, stream>>>(xb, wb,              bq, qb, D_, D_, D_, D_, 1.f, 0, 0, 0);
    gemm_bt<true, true><<<g1, blk, 0, stream>>>(xb, wb + D_ * D_,     bk, kb, D_, D_, D_, D_, 1.f, 0, 0, 0);
    gemm_bt<true, true><<<g1, blk, 0, stream>>>(xb, wb + 2 * D_ * D_, bv, vb, D_, D_, D_, D_, 1.f, 0, 0, 0);

    transpose_v<<<dim3(S_ / 64, D_ / 64, B_), blk, 0, stream>>>(vb, vt);

    // scores = scale * q k^T : M = N = 2048, K = 1024, per batch
    dim3 g2(16, 16, B_);
    gemm_bt<false, false><<<g2, blk, 0, stream>>>(qb, kb, nullptr, sc, D_, D_, S_, D_, 0.03125f,
                                                  (size_t)S_ * D_, (size_t)S_ * D_, (size_t)S_ * S_);

    softmax_rows<<<dim3(B_ * S_, 1, 1), blk, 0, stream>>>(sc);

    // out = P @ V : A = bf16 P rows (stride 4096 within sc buffer), B = vt rows, K = 2048
    dim3 g4(16, 8, B_);
    gemm_bt<false, false><<<g4, blk, 0, stream>>>((const unsigned short*)sc, vt, nullptr, out,
                                                  2 * S_, S_, D_, S_, 1.f,
                                                  (size_t)S_ * S_ * 2, (size_t)S_ * D_, (size_t)S_ * D_);
}

// Round 3
// 267.371 us; speedup vs baseline: 5.9899x; 1.2139x over previous
//
#include <hip/hip_runtime.h>
#include <math.h>

typedef float  f4     __attribute__((ext_vector_type(4)));
typedef float  f32x4  __attribute__((ext_vector_type(4)));
typedef short  bf16x8 __attribute__((ext_vector_type(8)));
typedef unsigned short u16x8 __attribute__((ext_vector_type(8)));

#define S_ 2048
#define B_ 4
#define D_ 1024

__device__ __forceinline__ unsigned short f2bf(float f) {
    unsigned u = __builtin_bit_cast(unsigned, f);
    u = (u + 0x7FFFu + ((u >> 16) & 1u)) >> 16;
    return (unsigned short)u;
}

#define GLOAD16(gsrc, ldst) \
    __builtin_amdgcn_global_load_lds((const __attribute__((address_space(1))) void*)(gsrc), \
                                     (__attribute__((address_space(3))) void*)(ldst), 16, 0, 0)

// ---------------------------------------------------------------------------
// Converters
// ---------------------------------------------------------------------------

// x (S,B,D) f32 -> xb (B,S,D) bf16
__global__ __launch_bounds__(128)
void convert_x(const float* __restrict__ x, unsigned short* __restrict__ xb)
{
    const int bid = blockIdx.x;
    const int b = bid & (B_ - 1);
    const int s = bid >> 2;
    const int t = threadIdx.x;
    const float* in = x + (size_t)bid * D_ + t * 8;
    unsigned short* out = xb + ((size_t)b * S_ + s) * D_ + t * 8;
    f4 lo = *(const f4*)in;
    f4 hi = *(const f4*)(in + 4);
    u16x8 o;
#pragma unroll
    for (int j = 0; j < 4; j++) { o[j] = f2bf(lo[j]); o[4 + j] = f2bf(hi[j]); }
    *(u16x8*)out = o;
}

// W (D,D) f32 x3 -> wcat bf16 [3072][1024]
__global__ __launch_bounds__(256)
void convert_w(const float* __restrict__ W0, const float* __restrict__ W1,
               const float* __restrict__ W2, unsigned short* __restrict__ dst)
{
    const float* src = (blockIdx.z == 0) ? W0 : (blockIdx.z == 1) ? W1 : W2;
    unsigned short* d = dst + (size_t)blockIdx.z * D_ * D_;
    size_t i = ((size_t)blockIdx.x * 256 + threadIdx.x) * 8;
    f4 lo = *(const f4*)(src + i);
    f4 hi = *(const f4*)(src + i + 4);
    u16x8 o;
#pragma unroll
    for (int j = 0; j < 4; j++) { o[j] = f2bf(lo[j]); o[4 + j] = f2bf(hi[j]); }
    *(u16x8*)(d + i) = o;
}

// bq,bk,bv (1024 f32 each) -> bcat[3072] f32
__global__ __launch_bounds__(256)
void convert_bias(const float* __restrict__ b0, const float* __restrict__ b1,
                  const float* __restrict__ b2, float* __restrict__ bcat)
{
    int i = blockIdx.x * 256 + threadIdx.x;   // grid 12 blocks
    int z = i >> 10, j = i & 1023;
    bcat[i] = (z == 0) ? b0[j] : (z == 1) ? b1[j] : b2[j];
}

// V columns of qkv (stride 3072, col offset 2048) -> vt (B,D,S) bf16
__global__ __launch_bounds__(256)
void transpose_v(const unsigned short* __restrict__ qkv, unsigned short* __restrict__ vt)
{
    __shared__ unsigned short tile[64][72];
    const int t = threadIdx.x;
    const int s0 = blockIdx.x * 64, d0 = blockIdx.y * 64, b = blockIdx.z;
    const int rr = t >> 3, c8 = (t & 7) * 8;
#pragma unroll
    for (int p = 0; p < 2; p++) {
        int r = rr + p * 32;
        u16x8 v = *(const u16x8*)(qkv + ((size_t)b * S_ + s0 + r) * 3072 + 2048 + d0 + c8);
#pragma unroll
        for (int j = 0; j < 8; j++) tile[r][c8 + j] = v[j];
    }
    __syncthreads();
#pragma unroll
    for (int p = 0; p < 2; p++) {
        int r = rr + p * 32;   // d within tile
        u16x8 o;
#pragma unroll
        for (int j = 0; j < 8; j++) o[j] = tile[c8 + j][r];
        *(u16x8*)(vt + ((size_t)b * D_ + d0 + r) * S_ + s0 + c8) = o;
    }
}

// ---------------------------------------------------------------------------
// Pipelined NT GEMM: C = alpha * A B^T (+bias). A: MxK rows(lda), B: NxK rows(ldb),
// bf16. BK=64. Double-buffered LDS, issue-early/wait-late global_load_lds,
// one vmcnt(0)+s_barrier per K-tile, T2 xor-swizzle, T5 setprio, T1 XCD swizzle.
// ---------------------------------------------------------------------------
template<int BM, int BN, int WM, int WN, bool BIAS, bool OBF16>
__global__ __launch_bounds__(WM*WN*64, 2)
void gemm2(const unsigned short* __restrict__ A, const unsigned short* __restrict__ B,
           const float* __restrict__ bias, void* __restrict__ C,
           int lda, int ldb, int ldc, int K, float alpha,
           size_t sA, size_t sB, size_t sC)
{
    constexpr int T   = WM * WN * 64;
    constexpr int WTM = BM / WM, WTN = BN / WN;
    constexpr int MR  = WTM / 16, NR = WTN / 16;
    constexpr int MH  = MR / 2,  NH = NR / 2;
    constexpr int ABYTES = BM * 128;           // A-tile bytes (BK=64 -> 128B rows)
    constexpr int BUFB   = (BM + BN) * 128;    // one K-tile buffer (A+B)

    __shared__ char sm[2 * BUFB] __attribute__((aligned(128)));

    const int t  = threadIdx.x;
    const int w  = t >> 6, ln = t & 63;
    const int wr = w / WN, wc = w % WN;
    const int c15 = ln & 15, k16 = ln >> 4;

    // T1: bijective XCD swizzle over the xy-linear id (nwg % 8 == 0 for all grids)
    const int gx  = gridDim.x;
    const int nwg = gx * gridDim.y;
    const int l0  = blockIdx.y * gx + blockIdx.x;
    const int cpx = nwg >> 3;
    const int lsw = (l0 & 7) * cpx + (l0 >> 3);
    const int m0  = (lsw % gx) * BM;
    const int n0  = (lsw / gx) * BN;

    const unsigned short* Ab = A + blockIdx.z * sA;
    const unsigned short* Bb = B + blockIdx.z * sB;

    // staging: thread t owns LDS bytes [(l*T+t)*16, +16) (linear dest);
    // global source pre-swizzled: q = p ^ (((p>>9)&3)<<5)  (tile-local, involution)
    const char* srcp[8];
    int ldso[8];
#pragma unroll
    for (int l = 0; l < 8; l++) {
        int p = (l * T + t) * 16;
        int q = p ^ (((p >> 9) & 3) << 5);
        if (q < ABYTES) {
            int r = q >> 7, cb = q & 127;
            srcp[l] = (const char*)(Ab + (size_t)(m0 + r) * lda) + cb;
        } else {
            int q2 = q - ABYTES;
            int r = q2 >> 7, cb = q2 & 127;
            srcp[l] = (const char*)(Bb + (size_t)(n0 + r) * ldb) + cb;
        }
        ldso[l] = (l * T + (t & ~63)) * 16;    // wave-uniform base; HW adds lane*16
    }

    // ds_read bases (swizzled): frag addr = base_k + frag*2048 (+ cur*BUFB)
    const int rbA   = (wr * WTM + c15) * 128 + k16 * 16;
    const int xorA  = ((rbA >> 9) & 3) << 5;
    const int bA0   = rbA ^ xorA;
    const int bA1   = (rbA + 64) ^ xorA;
    const int rbB   = (wc * WTN + c15) * 128 + k16 * 16;     // tile-local
    const int xorB  = ((rbB >> 9) & 3) << 5;
    const int bB0   = ABYTES + (rbB ^ xorB);
    const int bB1   = ABYTES + ((rbB + 64) ^ xorB);

    f32x4 acc[MR][NR];
#pragma unroll
    for (int i = 0; i < MR; i++)
#pragma unroll
        for (int j = 0; j < NR; j++) acc[i][j] = (f32x4)0.f;

    // prologue: stage K-tile 0 into buf0
#pragma unroll
    for (int l = 0; l < 8; l++) GLOAD16(srcp[l], sm + ldso[l]);

    const int NT = K >> 6;
    int cur = 0;
    for (int kt = 0; kt < NT; ++kt) {
        asm volatile("s_waitcnt vmcnt(0)" ::: "memory");  // buf[cur] landed (only its 8 loads outstanding)
        __builtin_amdgcn_s_barrier();                     // all waves' stages landed; prev reads of buf[cur^1] done
        const char* rb  = sm + cur * BUFB;
        char*       wbuf = sm + (cur ^ 1) * BUFB;
        const size_t kbn = (size_t)(kt + 1) * 128;
        const bool  st  = (kt + 1 < NT);

        bf16x8 Bfr[2][NH][2];
        int ph = 0;
#pragma unroll
        for (int mh = 0; mh < 2; mh++) {
            bf16x8 Afr[MH][2];
#pragma unroll
            for (int i = 0; i < MH; i++) {
                Afr[i][0] = *(const bf16x8*)(rb + bA0 + (mh * MH + i) * 2048);
                Afr[i][1] = *(const bf16x8*)(rb + bA1 + (mh * MH + i) * 2048);
            }
#pragma unroll
            for (int nh = 0; nh < 2; nh++) {
                // issue-early staging: phase0 -> loads 0..3, phase1 -> loads 4..7
                if (st && ph == 0) {
                    GLOAD16(srcp[0] + kbn, wbuf + ldso[0]);
                    GLOAD16(srcp[1] + kbn, wbuf + ldso[1]);
                    GLOAD16(srcp[2] + kbn, wbuf + ldso[2]);
                    GLOAD16(srcp[3] + kbn, wbuf + ldso[3]);
                }
                if (st && ph == 1) {
                    GLOAD16(srcp[4] + kbn, wbuf + ldso[4]);
                    GLOAD16(srcp[5] + kbn, wbuf + ldso[5]);
                    GLOAD16(srcp[6] + kbn, wbuf + ldso[6]);
                    GLOAD16(srcp[7] + kbn, wbuf + ldso[7]);
                }
                if (mh == 0) {
#pragma unroll
                    for (int j = 0; j < NH; j++) {
                        Bfr[nh][j][0] = *(const bf16x8*)(rb + bB0 + (nh * NH + j) * 2048);
                        Bfr[nh][j][1] = *(const bf16x8*)(rb + bB1 + (nh * NH + j) * 2048);
                    }
                }
                __builtin_amdgcn_s_setprio(1);
#pragma unroll
                for (int i = 0; i < MH; i++)
#pragma unroll
                    for (int j = 0; j < NH; j++) {
                        acc[mh*MH+i][nh*NH+j] = __builtin_amdgcn_mfma_f32_16x16x32_bf16(
                            Afr[i][0], Bfr[nh][j][0], acc[mh*MH+i][nh*NH+j], 0, 0, 0);
                        acc[mh*MH+i][nh*NH+j] = __builtin_amdgcn_mfma_f32_16x16x32_bf16(
                            Afr[i][1], Bfr[nh][j][1], acc[mh*MH+i][nh*NH+j], 0, 0, 0);
                    }
                __builtin_amdgcn_s_setprio(0);
                ph++;
            }
        }
        cur ^= 1;
    }

    // epilogue
    float bvv[NR];
#pragma unroll
    for (int j = 0; j < NR; j++)
        bvv[j] = BIAS ? bias[n0 + wc * WTN + j * 16 + c15] : 0.f;

#pragma unroll
    for (int mi = 0; mi < MR; mi++) {
        const int row = m0 + wr * WTM + mi * 16 + k16 * 4;
#pragma unroll
        for (int nj = 0; nj < NR; nj++) {
            const int col = n0 + wc * WTN + nj * 16 + c15;
#pragma unroll
            for (int r = 0; r < 4; r++) {
                float vv = acc[mi][nj][r] * alpha + bvv[nj];
                if (OBF16)
                    ((unsigned short*)C + blockIdx.z * sC)[(size_t)(row + r) * ldc + col] = f2bf(vv);
                else
                    ((float*)C + blockIdx.z * sC)[(size_t)(row + r) * ldc + col] = vv;
            }
        }
    }
}

// ---------------------------------------------------------------------------
// Row softmax: read f32 row of 2048, write bf16 row IN PLACE
// ---------------------------------------------------------------------------
__global__ __launch_bounds__(256)
void softmax_rows(float* __restrict__ P)
{
    float* p = P + (size_t)blockIdx.x * S_;
    const int t = threadIdx.x;

    f4 v0 = *(f4*)&p[t * 8];
    f4 v1 = *(f4*)&p[t * 8 + 4];

    float mx = v0[0];
#pragma unroll
    for (int j = 0; j < 4; j++) { mx = fmaxf(mx, v0[j]); mx = fmaxf(mx, v1[j]); }
#pragma unroll
    for (int off = 32; off > 0; off >>= 1) mx = fmaxf(mx, __shfl_xor(mx, off));

    __shared__ float rmax[4], rsum[4];
    if ((t & 63) == 0) rmax[t >> 6] = mx;
    __syncthreads();
    mx = fmaxf(fmaxf(rmax[0], rmax[1]), fmaxf(rmax[2], rmax[3]));

    float sum = 0.f;
#pragma unroll
    for (int j = 0; j < 4; j++) {
        v0[j] = __expf(v0[j] - mx); sum += v0[j];
        v1[j] = __expf(v1[j] - mx); sum += v1[j];
    }
#pragma unroll
    for (int off = 32; off > 0; off >>= 1) sum += __shfl_xor(sum, off);
    if ((t & 63) == 0) rsum[t >> 6] = sum;
    __syncthreads();
    sum = rsum[0] + rsum[1] + rsum[2] + rsum[3];

    float inv = 1.f / sum;
    unsigned short* ob = (unsigned short*)p;
    u16x8 o;
#pragma unroll
    for (int j = 0; j < 4; j++) { o[j] = f2bf(v0[j] * inv); o[4 + j] = f2bf(v1[j] * inv); }
    __syncthreads();
    *(u16x8*)&ob[t * 8] = o;
}

// ---------------------------------------------------------------------------

extern "C" void kernel_launch(void* const* d_in, const int* in_sizes, int n_in,
                              void* d_out, int out_size, void* d_ws, size_t ws_size,
                              hipStream_t stream)
{
    const float* x  = (const float*)d_in[0];
    const float* Wq = (const float*)d_in[1];
    const float* bq = (const float*)d_in[2];
    const float* Wk = (const float*)d_in[3];
    const float* bk = (const float*)d_in[4];
    const float* Wv = (const float*)d_in[5];
    const float* bv = (const float*)d_in[6];
    float* out = (float*)d_out;

    const size_t nTok = (size_t)B_ * S_;          // 8192
    char* ws = (char*)d_ws;

    unsigned short* xb   = (unsigned short*)ws;   ws += nTok * D_ * 2;            // 16 MB
    unsigned short* wcat = (unsigned short*)ws;   ws += (size_t)3 * D_ * D_ * 2;  // 6 MB
    float*          bcat = (float*)ws;            ws += 3 * D_ * 4;               // 12 KB
    unsigned short* qkv  = (unsigned short*)ws;   ws += nTok * 3 * D_ * 2;        // 48 MB
    unsigned short* vt   = (unsigned short*)ws;   ws += nTok * D_ * 2;            // 16 MB
    float*          sc   = (float*)ws;            ws += (size_t)B_ * S_ * S_ * 4; // 64 MB
    if ((size_t)(ws - (char*)d_ws) > ws_size) return;                             // ~157 MB

    convert_x<<<dim3(S_ * B_), dim3(128), 0, stream>>>(x, xb);
    convert_w<<<dim3(512, 1, 3), dim3(256), 0, stream>>>(Wq, Wk, Wv, wcat);
    convert_bias<<<dim3(12), dim3(256), 0, stream>>>(bq, bk, bv, bcat);

    // Fused QKV: [8192 x 3072] = xb [8192x1024] @ wcat^T, +bias, bf16 out
    gemm2<256, 256, 2, 4, true, true><<<dim3(32, 12, 1), dim3(512), 0, stream>>>(
        xb, wcat, bcat, qkv, D_, D_, 3 * D_, D_, 1.f, 0, 0, 0);

    transpose_v<<<dim3(S_ / 64, D_ / 64, B_), dim3(256), 0, stream>>>(qkv, vt);

    // scores = scale * q k^T per batch: q = qkv cols[0:1024), k = cols[1024:2048)
    gemm2<256, 256, 2, 4, false, false><<<dim3(8, 8, B_), dim3(512), 0, stream>>>(
        qkv, qkv + D_, nullptr, sc, 3 * D_, 3 * D_, S_, D_, 0.03125f,
        (size_t)S_ * 3 * D_, (size_t)S_ * 3 * D_, (size_t)S_ * S_);

    softmax_rows<<<dim3(B_ * S_), dim3(256), 0, stream>>>(sc);

    // out = P @ V^T_vt : A = bf16 P rows (pitch 4096 ushorts), B = vt (B,D,S)
    gemm2<128, 128, 2, 2, false, false><<<dim3(16, 8, B_), dim3(256), 0, stream>>>(
        (const unsigned short*)sc, vt, nullptr, out, 2 * S_, S_, D_, S_, 1.f,
        (size_t)S_ * S_ * 2, (size_t)D_ * S_, (size_t)S_ * D_);
}